// Round 6
// baseline (75.002 us; speedup 1.0000x reference)
//
#include <hip/hip_runtime.h>

#define F_BINS  257
#define T_STEPS 65536
#define N_ACT   256
#define NBLK    1024          // k_gemm blocks, 64 t-columns each
#define AT_PITCH 296          // ushort cols per At row (>=288 for kk=8 read)
#define XO_CHUNK 4112         // float4 per block: 257*65536/4/1024, exact

typedef float f32x4 __attribute__((ext_vector_type(4)));
typedef short s16x8 __attribute__((ext_vector_type(8)));
typedef unsigned u32x4 __attribute__((ext_vector_type(4)));
typedef unsigned long long u64;

// ws layout:
//   [0]      double Sc
//   [8]      double Sb
//   [64]     unsigned mask[8]          (final selected-action bitmask)
//   [1024]   u64 argkey[65536]         (per-t argmax key; memset 0 = -inf)
//   [528384] uchar Gfrag[147456]       (B fragments: [kk][ng][lane][16B])
#define WS_SC    0
#define WS_SB    8
#define WS_MASK  64
#define WS_KEY   1024
#define WS_GFRAG 528384

__device__ __forceinline__ unsigned short f2bf_rne(float x) {
  unsigned u = __builtin_bit_cast(unsigned, x);
  return (unsigned short)((u + 0x7FFFu + ((u >> 16) & 1u)) >> 16);
}
// bf16(hi)<<16 | bf16(lo) by truncation: one v_perm_b32
__device__ __forceinline__ unsigned pack_bf(float hi, float lo) {
  return __builtin_amdgcn_perm(__builtin_bit_cast(unsigned, hi),
                               __builtin_bit_cast(unsigned, lo), 0x07060302u);
}
// monotonic float->u32 (order-preserving, finite inputs)
__device__ __forceinline__ unsigned mono(float v) {
  unsigned u = __builtin_bit_cast(unsigned, v);
  return u ^ (unsigned)(((int)u >> 31) | (int)0x80000000);
}

// ---------------------------------------------------------------------------
// Build B fragments: Gfrag[((kk*16+ng)*64+lane)*16] = 8 bf16 of
// G[f = 32kk+8(lane>>4)+j][a = 16ng+(lane&15)], zero for f>=257.
// ---------------------------------------------------------------------------
__global__ __launch_bounds__(256) void k_prep(const float* __restrict__ G,
                                              unsigned char* __restrict__ gfrag) {
  const int u = blockIdx.x * 256 + threadIdx.x;   // 0..9215
  const int lane = u & 63, ng = (u >> 6) & 15, kk = u >> 10;
  const int r16 = lane & 15, g = lane >> 4;
  const int a = ng * 16 + r16;
  unsigned short h[8];
#pragma unroll
  for (int j = 0; j < 8; ++j) {
    const int f = kk * 32 + 8 * g + j;
    h[j] = (f < F_BINS) ? f2bf_rne(G[f * N_ACT + a]) : (unsigned short)0;
  }
  u32x4 w;
#pragma unroll
  for (int i = 0; i < 4; ++i)
    w[i] = (unsigned)h[2 * i] | ((unsigned)h[2 * i + 1] << 16);
  *(u32x4*)(gfrag + (size_t)u * 16) = w;
}

// ---------------------------------------------------------------------------
// GEMM+argmax+xo^2. A: 64t x 257f staged to LDS as bf16 once (lgkmcnt-only
// inner loop). B: each wave holds its 64-action quarter in 144 VGPRs.
// Inner loop: 36 ds_read_b128 + 144 MFMA, zero global traffic, zero barriers.
// ---------------------------------------------------------------------------
__global__ __launch_bounds__(256, 2) void k_gemm(
    const float* __restrict__ xs, const float* __restrict__ xo,
    const unsigned char* __restrict__ gfrag,
    u64* __restrict__ argkey, double* __restrict__ Sb) {
  const int tid = threadIdx.x, lane = tid & 63, wv = tid >> 6;
  const int g = lane >> 4, r16 = lane & 15;
  const int t0 = blockIdx.x * 64;

  __shared__ unsigned short At[64 * AT_PITCH];   // 37,888 B
  __shared__ double sd[4];

  // ---- stage A: xs[f][t0..t0+63] -> At[t][f] bf16; cols >=257 zeroed ----
  {
    const int tl = tid & 63, f0 = tid >> 6;      // wave-uniform f-pair index
#pragma unroll 4
    for (int fp = f0; fp < 148; fp += 4) {
      const int f = fp * 2;
      float v0 = 0.f, v1 = 0.f;
      if (f < F_BINS)     v0 = xs[(size_t)f * T_STEPS + t0 + tl];
      if (f + 1 < F_BINS) v1 = xs[(size_t)(f + 1) * T_STEPS + t0 + tl];
      *(unsigned*)&At[tl * AT_PITCH + f] = pack_bf(v1, v0);
    }
  }

  // ---- B quarter -> registers (36 x 16B, L2-resident) ----
  s16x8 b[9][4];
#pragma unroll
  for (int kk = 0; kk < 9; ++kk)
#pragma unroll
    for (int n = 0; n < 4; ++n)
      b[kk][n] = *(const s16x8*)(gfrag +
          (size_t)((kk * 16 + 4 * wv + n) * 64 + lane) * 16);

  __syncthreads();   // At fully staged

  // ---- main loop ----
  f32x4 acc[4][4];   // [tau(t-tile)][n(action-tile)]
#pragma unroll
  for (int tau = 0; tau < 4; ++tau)
#pragma unroll
    for (int n = 0; n < 4; ++n) acc[tau][n] = (f32x4){0.f, 0.f, 0.f, 0.f};

#pragma unroll
  for (int kk = 0; kk < 9; ++kk) {
    s16x8 af[4];
#pragma unroll
    for (int tau = 0; tau < 4; ++tau)
      af[tau] = *(const s16x8*)&At[(16 * tau + r16) * AT_PITCH + kk * 32 + 8 * g];
#pragma unroll
    for (int tau = 0; tau < 4; ++tau)
#pragma unroll
      for (int n = 0; n < 4; ++n)
        acc[tau][n] = __builtin_amdgcn_mfma_f32_16x16x32_bf16(
            af[tau], b[kk][n], acc[tau][n], 0, 0, 0);
  }

  // ---- argmax: per (tau,q) row t = t0+16tau+4g+q over this wave's 64 a ----
#pragma unroll
  for (int tau = 0; tau < 4; ++tau) {
#pragma unroll
    for (int q = 0; q < 4; ++q) {
      float bv = acc[tau][0][q];
      int   bc = 64 * wv + r16;
#pragma unroll
      for (int n = 1; n < 4; ++n) {
        const int c = 64 * wv + 16 * n + r16;
        if (acc[tau][n][q] > bv) { bv = acc[tau][n][q]; bc = c; }
      }
      u64 key = ((u64)mono(bv) << 32) | (unsigned)(~bc);
#pragma unroll
      for (int m = 1; m <= 8; m <<= 1) {
        const u64 ok = __shfl_xor(key, m, 64);
        if (ok > key) key = ok;
      }
      if (r16 == 0)
        atomicMax(&argkey[t0 + 16 * tau + 4 * g + q], key);
    }
  }

  // ---- fused sum of x_out^2: contiguous per-block float4 chunk ----
  const float4* xo4 = (const float4*)xo;
  const size_t base = (size_t)blockIdx.x * XO_CHUNK;
  double ds = 0.0;
#pragma unroll 4
  for (int i = tid; i < XO_CHUNK; i += 256) {
    const float4 v = xo4[base + i];
    ds += (double)fmaf(v.x, v.x, v.y * v.y) + (double)fmaf(v.z, v.z, v.w * v.w);
  }
#pragma unroll
  for (int off = 32; off; off >>= 1) ds += __shfl_down(ds, off);
  if (lane == 0) sd[wv] = ds;
  __syncthreads();
  if (tid == 0) atomicAdd(Sb, sd[0] + sd[1] + sd[2] + sd[3]);
}

// ---------------------------------------------------------------------------
// Build the 8-word selected-action bitmask from argkey.
// ---------------------------------------------------------------------------
__global__ __launch_bounds__(256) void k_mask(const u64* __restrict__ argkey,
                                              unsigned* __restrict__ mask) {
  __shared__ unsigned lm[8];
  const int tid = threadIdx.x;
  if (tid < 8) lm[tid] = 0u;
  __syncthreads();
  const int t = blockIdx.x * 256 + tid;
  const unsigned bc = ~(unsigned)(argkey[t] & 0xFFFFFFFFull);
  atomicOr(&lm[(bc >> 5) & 7], 1u << (bc & 31));
  __syncthreads();
  if (tid < 8 && lm[tid]) atomicOr(&mask[tid], lm[tid]);
}

// ---------------------------------------------------------------------------
// Correction for selected columns t = a < 256:
//   Sc += sum_f (G*xs)^2 - 2*(G*xs)*xo
// ---------------------------------------------------------------------------
__global__ __launch_bounds__(256) void k_corr(
    const float* __restrict__ xs, const float* __restrict__ xo,
    const float* __restrict__ G, const unsigned* __restrict__ mask,
    double* __restrict__ Sc) {
  const int f = blockIdx.x, a = threadIdx.x;
  const bool sel = (mask[a >> 5] >> (a & 31)) & 1u;
  const float gv  = G[f * N_ACT + a];
  const float xsv = xs[(size_t)f * T_STEPS + a];
  const float xov = xo[(size_t)f * T_STEPS + a];
  const float gx  = gv * xsv;
  double acc = sel ? (double)(gx * (gx - 2.f * xov)) : 0.0;
#pragma unroll
  for (int off = 32; off; off >>= 1) acc += __shfl_down(acc, off);
  __shared__ double sdc[4];
  if ((threadIdx.x & 63) == 0) sdc[threadIdx.x >> 6] = acc;
  __syncthreads();
  if (threadIdx.x == 0) atomicAdd(Sc, sdc[0] + sdc[1] + sdc[2] + sdc[3]);
}

__global__ void k_final(const double* __restrict__ Sb,
                        const double* __restrict__ Sc,
                        float* __restrict__ out) {
  out[0] = (float)((Sb[0] + Sc[0]) / ((double)F_BINS * (double)T_STEPS));
}

extern "C" void kernel_launch(void* const* d_in, const int* in_sizes, int n_in,
                              void* d_out, int out_size, void* d_ws, size_t ws_size,
                              hipStream_t stream) {
  const float* x_out    = (const float*)d_in[0];
  const float* x_source = (const float*)d_in[1];
  // d_in[2] (x_clean) is dead: argmin_a(clean_sum - proj) == argmax_a proj
  const float* G        = (const float*)d_in[3];

  char* ws = (char*)d_ws;
  double*        Sc     = (double*)(ws + WS_SC);
  double*        Sb     = (double*)(ws + WS_SB);
  unsigned*      mask   = (unsigned*)(ws + WS_MASK);
  u64*           argkey = (u64*)(ws + WS_KEY);
  unsigned char* gfrag  = (unsigned char*)(ws + WS_GFRAG);

  hipMemsetAsync(d_ws, 0, WS_KEY + (size_t)T_STEPS * 8, stream);  // Sc,Sb,mask,argkey
  k_prep <<<36, 256, 0, stream>>>(G, gfrag);
  k_gemm <<<NBLK, 256, 0, stream>>>(x_source, x_out, gfrag, argkey, Sb);
  k_mask <<<T_STEPS / 256, 256, 0, stream>>>(argkey, mask);
  k_corr <<<F_BINS, 256, 0, stream>>>(x_source, x_out, G, mask, Sc);
  k_final<<<1, 1, 0, stream>>>(Sb, Sc, (float*)d_out);
}

// Round 7
// 65.695 us; speedup vs baseline: 1.1417x; 1.1417x over previous
//
#include <hip/hip_runtime.h>

#define F_BINS  257
#define T_STEPS 65536
#define N_ACT   256
#define NBLK    1024          // k_gemm blocks, 64 t-columns each
#define XO_CHUNK 4112         // float4 per block: 257*65536/4/1024, exact

typedef float f32x4 __attribute__((ext_vector_type(4)));
typedef short s16x8 __attribute__((ext_vector_type(8)));
typedef unsigned u32x4 __attribute__((ext_vector_type(4)));

// ws layout:
//   [0]      double Sc
//   [8]      double Sb
//   [16384]  unsigned maskp[NBLK*8]      (per-block selected-action bitmask)
//   [65536]  uchar Gfrag[147456]         (B frags: [kk][ng][lane][16B])
#define WS_SC    0
#define WS_SB    8
#define WS_MASK  16384
#define WS_GFRAG 65536

__device__ __forceinline__ unsigned short f2bf_rne(float x) {
  unsigned u = __builtin_bit_cast(unsigned, x);
  return (unsigned short)((u + 0x7FFFu + ((u >> 16) & 1u)) >> 16);
}
// bf16(hi)<<16 | bf16(lo) by truncation: one v_perm_b32
__device__ __forceinline__ unsigned pack_bf(float hi, float lo) {
  return __builtin_amdgcn_perm(__builtin_bit_cast(unsigned, hi),
                               __builtin_bit_cast(unsigned, lo), 0x07060302u);
}
#define PACK8(v) __builtin_bit_cast(s16x8, (u32x4){                          \
      pack_bf((v)[1], (v)[0]), pack_bf((v)[3], (v)[2]),                      \
      pack_bf((v)[5], (v)[4]), pack_bf((v)[7], (v)[6])})

// ---------------------------------------------------------------------------
// Build B fragments in MFMA fragment order:
// Gfrag[((kk*16+ng)*64+lane)*16] = 8 bf16 of G[f=32kk+8(lane>>4)+j][a=16ng+(lane&15)]
// ---------------------------------------------------------------------------
__global__ __launch_bounds__(256) void k_prep(const float* __restrict__ G,
                                              unsigned char* __restrict__ gfrag) {
  const int u = blockIdx.x * 256 + threadIdx.x;   // 0..9215
  const int lane = u & 63, ng = (u >> 6) & 15, kk = u >> 10;
  const int r16 = lane & 15, g = lane >> 4;
  const int a = ng * 16 + r16;
  unsigned short h[8];
#pragma unroll
  for (int j = 0; j < 8; ++j) {
    const int f = kk * 32 + 8 * g + j;
    h[j] = (f < F_BINS) ? f2bf_rne(G[f * N_ACT + a]) : (unsigned short)0;
  }
  u32x4 w;
#pragma unroll
  for (int i = 0; i < 4; ++i)
    w[i] = (unsigned)h[2 * i] | ((unsigned)h[2 * i + 1] << 16);
  *(u32x4*)(gfrag + (size_t)u * 16) = w;
}

// ---------------------------------------------------------------------------
// GEMM+argmax+xo^2.
//   A: 72 global loads -> 36 VGPR bf16 frags, fully preloaded (deep MLP).
//   B: Gfrag kk-slices (16KB) -> LDS 3-buffer ring via global_load_lds
//      (linear, fragment-order => conflict-free ds_read_b128), distance-2
//      prefetch, vmcnt(4) per iter, ONE barrier per iter (stage after bar).
// Wave wv owns t-rows [t0+16wv,+16) x all 256 actions; acc = 16 f32x4.
// ---------------------------------------------------------------------------
__global__ __launch_bounds__(256, 2) void k_gemm(
    const float* __restrict__ xs, const float* __restrict__ xo,
    const unsigned char* __restrict__ gfrag,
    unsigned* __restrict__ maskp, double* __restrict__ Sb) {
  const int tid = threadIdx.x, lane = tid & 63, wv = tid >> 6;
  const int g = lane >> 4, r16 = lane & 15;
  const int t0 = blockIdx.x * 64;
  const int trow = t0 + wv * 16 + r16;

  __shared__ __align__(16) unsigned char Bb[3][16384];
  __shared__ unsigned lmask[8];
  __shared__ double sd[4];
  if (tid < 8) lmask[tid] = 0u;

  // stage one 16KB kk-slice: 16 x 1KB; wave wv does ng = 4wv..4wv+3
#define STAGE(buf, kkv)                                                       \
  {                                                                           \
    _Pragma("unroll") for (int i = 0; i < 4; ++i) {                           \
      const unsigned char* src = gfrag +                                      \
          (size_t)((((kkv) * 16 + 4 * wv + i) * 64 + lane) * 16);             \
      unsigned char* dst = &Bb[(buf)][(4 * wv + i) * 1024];                   \
      __builtin_amdgcn_global_load_lds(                                       \
          (const __attribute__((address_space(1))) unsigned*)src,             \
          (__attribute__((address_space(3))) unsigned*)dst, 16, 0, 0);        \
    }                                                                         \
  }

  STAGE(0, 0)
  STAGE(1, 1)

  // ---- A preload: 72 independent loads, then pack ----
  float va[9][8];
#pragma unroll
  for (int kk = 0; kk < 9; ++kk)
#pragma unroll
    for (int j = 0; j < 8; ++j) {
      int f = 32 * kk + 8 * g + j;
      if (kk == 8) f = f > 256 ? 256 : f;  // Gfrag zero rows kill garbage
      va[kk][j] = xs[(size_t)f * T_STEPS + trow];
    }
  s16x8 af[9];
#pragma unroll
  for (int kk = 0; kk < 9; ++kk) af[kk] = PACK8(va[kk]);

  f32x4 acc[16];
#pragma unroll
  for (int n = 0; n < 16; ++n) acc[n] = (f32x4){0.f, 0.f, 0.f, 0.f};

  // ---- main loop: 9 iters, 1 barrier each, LDS-only B reads ----
#pragma unroll
  for (int kk = 0; kk < 9; ++kk) {
    // wait this wave's own slice-kk stage (4 instrs; slice kk+1 may fly)
    if (kk < 8) asm volatile("s_waitcnt vmcnt(4)" ::: "memory");
    else        asm volatile("s_waitcnt vmcnt(0)" ::: "memory");
    __builtin_amdgcn_s_barrier();  // all waves staged slice kk; prior reads done
    if (kk <= 6) STAGE((kk + 2) % 3, kk + 2)   // safe: overwrites slice kk-1
    const unsigned char* bp = &Bb[kk % 3][lane * 16];
#pragma unroll
    for (int n = 0; n < 16; ++n) {
      const s16x8 bfr = *(const s16x8*)(bp + n * 1024);
      acc[n] = __builtin_amdgcn_mfma_f32_16x16x32_bf16(af[kk], bfr, acc[n], 0, 0, 0);
    }
  }
#undef STAGE

  // ---- argmax per row t = t0+16wv+4g+q over 256 actions ----
#pragma unroll
  for (int q = 0; q < 4; ++q) {
    float bv = acc[0][q];
    int   bc = r16;
#pragma unroll
    for (int n = 1; n < 16; ++n) {
      const int c = 16 * n + r16;
      if (acc[n][q] > bv) { bv = acc[n][q]; bc = c; }
    }
#pragma unroll
    for (int m = 1; m <= 8; m <<= 1) {
      const float ov = __shfl_xor(bv, m);
      const int   oc = __shfl_xor(bc, m);
      if (ov > bv || (ov == bv && oc < bc)) { bv = ov; bc = oc; }
    }
    if (r16 == 0) atomicOr(&lmask[bc >> 5], 1u << (bc & 31));
  }
  __syncthreads();
  if (tid < 8) maskp[blockIdx.x * 8 + tid] = lmask[tid];

  // ---- fused sum of x_out^2: contiguous per-block float4 chunk ----
  const float4* xo4 = (const float4*)xo;
  const size_t base = (size_t)blockIdx.x * XO_CHUNK;
  double ds = 0.0;
#pragma unroll 8
  for (int i = tid; i < XO_CHUNK; i += 256) {
    const float4 v = xo4[base + i];
    ds += (double)fmaf(v.x, v.x, v.y * v.y) + (double)fmaf(v.z, v.z, v.w * v.w);
  }
#pragma unroll
  for (int off = 32; off; off >>= 1) ds += __shfl_down(ds, off);
  if (lane == 0) sd[wv] = ds;
  __syncthreads();
  if (tid == 0) atomicAdd(Sb, sd[0] + sd[1] + sd[2] + sd[3]);
}

// ---------------------------------------------------------------------------
// OR-reduce per-block masks, then correction for selected columns t = a:
//   Sc += sum_f (G*xs)^2 - 2*(G*xs)*xo
// ---------------------------------------------------------------------------
__global__ __launch_bounds__(256) void k_corr(
    const float* __restrict__ xs, const float* __restrict__ xo,
    const float* __restrict__ G, const unsigned* __restrict__ maskp,
    double* __restrict__ Sc) {
  __shared__ unsigned m8[8];
  const int tid = threadIdx.x;
  if (tid < 8) m8[tid] = 0u;
  __syncthreads();
  unsigned m = 0;
  for (int b = tid >> 3; b < NBLK; b += 32) m |= maskp[b * 8 + (tid & 7)];
  atomicOr(&m8[tid & 7], m);
  __syncthreads();
  const int f = blockIdx.x, a = tid;
  const bool sel = (m8[a >> 5] >> (a & 31)) & 1u;
  const float gv  = G[f * N_ACT + a];
  const float xsv = xs[(size_t)f * T_STEPS + a];
  const float xov = xo[(size_t)f * T_STEPS + a];
  const float gx  = gv * xsv;
  double acc = sel ? (double)(gx * (gx - 2.f * xov)) : 0.0;
#pragma unroll
  for (int off = 32; off; off >>= 1) acc += __shfl_down(acc, off);
  __shared__ double sdc[4];
  if ((tid & 63) == 0) sdc[tid >> 6] = acc;
  __syncthreads();
  if (tid == 0) atomicAdd(Sc, sdc[0] + sdc[1] + sdc[2] + sdc[3]);
}

__global__ void k_final(const double* __restrict__ Sb,
                        const double* __restrict__ Sc,
                        float* __restrict__ out) {
  out[0] = (float)((Sb[0] + Sc[0]) / ((double)F_BINS * (double)T_STEPS));
}

extern "C" void kernel_launch(void* const* d_in, const int* in_sizes, int n_in,
                              void* d_out, int out_size, void* d_ws, size_t ws_size,
                              hipStream_t stream) {
  const float* x_out    = (const float*)d_in[0];
  const float* x_source = (const float*)d_in[1];
  // d_in[2] (x_clean) is dead: argmin_a(clean_sum - proj) == argmax_a proj
  const float* G        = (const float*)d_in[3];

  char* ws = (char*)d_ws;
  double*        Sc    = (double*)(ws + WS_SC);
  double*        Sb    = (double*)(ws + WS_SB);
  unsigned*      maskp = (unsigned*)(ws + WS_MASK);
  unsigned char* gfrag = (unsigned char*)(ws + WS_GFRAG);

  hipMemsetAsync(d_ws, 0, 64, stream);   // Sc, Sb
  k_prep <<<36, 256, 0, stream>>>(G, gfrag);
  k_gemm <<<NBLK, 256, 0, stream>>>(x_source, x_out, gfrag, maskp, Sb);
  k_corr <<<F_BINS, 256, 0, stream>>>(x_source, x_out, G, maskp, Sc);
  k_final<<<1, 1, 0, stream>>>(Sb, Sc, (float*)d_out);
}